// Round 6
// baseline (472.524 us; speedup 1.0000x reference)
//
#include <hip/hip_runtime.h>
#include <math.h>

// Problem constants (B=16, L=C=256 scan axis, dm=di=1024, n=2, dtr=64, k=4)
#define BATCH 16
#define LSEQ  256
#define DM    1024
#define DI    1024
#define NROWS (BATCH*LSEQ)   // 4096
#define DTR   64
#define TWO_DI 2048
#define NCH   16             // scan chunks
#define CHL   16             // chunk length (NCH*CHL == LSEQ)

typedef __attribute__((ext_vector_type(8))) short short8;
typedef __attribute__((ext_vector_type(4))) float floatx4;
typedef __attribute__((ext_vector_type(4))) unsigned short ushortx4;

__device__ __forceinline__ float siluf(float x) {
    return x / (1.0f + __expf(-x));
}
__device__ __forceinline__ float softplusf(float x) {
    return fmaxf(x, 0.0f) + log1pf(__expf(-fabsf(x)));
}
// fp32 -> bf16 (RNE), raw bits
__device__ __forceinline__ unsigned short f2bf(float f) {
    unsigned int u = __float_as_uint(f);
    u += 0x7fffu + ((u >> 16) & 1u);
    return (unsigned short)(u >> 16);
}
__device__ __forceinline__ float bf2f(unsigned short s) {
    return __uint_as_float(((unsigned int)s) << 16);
}
// async global->LDS, 16B per lane; LDS dest = wave-uniform base + lane*16
__device__ __forceinline__ void async16(const short* g, short* l) {
    __builtin_amdgcn_global_load_lds(
        (const __attribute__((address_space(1))) unsigned int*)g,
        (__attribute__((address_space(3))) unsigned int*)l,
        16, 0, 0);
}

// ---------------------------------------------------------------------------
// cast8: all fp32->bf16 input casts in ONE dispatch. 1024 elts per block.
// Segments (blocks): x 4096 | m1Win 2048 | m1Wout 1024 | m2Win 2048 |
//                    m2Wout 1024 | Wspa 1024 | Wmid 64 | Wres 64  = 11392
// ---------------------------------------------------------------------------
__global__ __launch_bounds__(256) void cast8(
    const float* __restrict__ x,    unsigned short* __restrict__ ox,
    const float* __restrict__ w1i,  unsigned short* __restrict__ o1i,
    const float* __restrict__ w1o,  unsigned short* __restrict__ o1o,
    const float* __restrict__ w2i,  unsigned short* __restrict__ o2i,
    const float* __restrict__ w2o,  unsigned short* __restrict__ o2o,
    const float* __restrict__ wsp,  unsigned short* __restrict__ osp,
    const float* __restrict__ wmd,  unsigned short* __restrict__ omd,
    const float* __restrict__ wrs,  unsigned short* __restrict__ ors)
{
    const int b = blockIdx.x;
    const float* in; unsigned short* out; int base;
    if      (b <  4096) { in = x;   out = ox;  base = 0; }
    else if (b <  6144) { in = w1i; out = o1i; base = 4096; }
    else if (b <  7168) { in = w1o; out = o1o; base = 6144; }
    else if (b <  9216) { in = w2i; out = o2i; base = 7168; }
    else if (b < 10240) { in = w2o; out = o2o; base = 9216; }
    else if (b < 11264) { in = wsp; out = osp; base = 10240; }
    else if (b < 11328) { in = wmd; out = omd; base = 11264; }
    else                { in = wrs; out = ors; base = 11328; }
    const size_t i = ((size_t)(b - base) * 256 + threadIdx.x) * 4;
    const float4 v = *(const float4*)(in + i);
    union { unsigned short s[4]; unsigned long long u; } p;
    p.s[0] = f2bf(v.x); p.s[1] = f2bf(v.y);
    p.s[2] = f2bf(v.z); p.s[3] = f2bf(v.w);
    *(unsigned long long*)(out + i) = p.u;
}

// ---------------------------------------------------------------------------
// Single-wave bf16 MFMA GEMM (nt): C[M,N] = A[M,K] @ W[N,K]^T.
// 64 threads = 1 wave per block, 64x64 tile, dbuf LDS (16 KB).
// m97 intensity (16 MFMA : 8 ds_read_b128) but barrier couples only ONE wave;
// 4-8 independent blocks/CU hide the vmcnt drain (m114 overlap).
// EP: 0=none, 1=softplus(v+bias[c]), 2=silu(v+bias[c]), 3=silu(v)
// OUT16: bf16 out. BATW: W,C batched by blockIdx.z. FIN: v=silu(Sadd+silu(v)).
// ---------------------------------------------------------------------------
template <int EP, int OUT16, int BATW, int FIN>
__global__ __launch_bounds__(64) void gemm1w(
    const short* __restrict__ A,
    const short* __restrict__ W,
    const float* __restrict__ bias,
    const float* __restrict__ Sadd,
    void* __restrict__ Cout,
    int M, int N, int K)
{
    __shared__ short As[2 * 64 * 32];
    __shared__ short Bs[2 * 64 * 32];

    const int bz = BATW ? blockIdx.z : 0;
    const short* Wb = W + (size_t)bz * N * K;
    const size_t cbase = (size_t)bz * M * N;

    const int lane = threadIdx.x;
    const int row0 = blockIdx.y * 64;
    const int col0 = blockIdx.x * 64;

    const int srow  = lane >> 2;         // 0..15
    const int skoff = (lane & 3) * 8;    // k elts
    const short* gA = A  + (size_t)(row0 + srow) * K + skoff;
    const short* gB = Wb + (size_t)(col0 + srow) * K + skoff;
    short* lA = As + srow * 32 + skoff;  // == As + lane*8 shorts (16 B)
    short* lB = Bs + srow * 32 + skoff;

    const int fr = lane & 15;
    const int fk = (lane >> 4) * 8;

    floatx4 acc[4][4] = {};

    #pragma unroll
    for (int r = 0; r < 4; r++) {
        async16(gA + (size_t)(r * 16) * K, lA + r * 16 * 32);
        async16(gB + (size_t)(r * 16) * K, lB + r * 16 * 32);
    }
    __syncthreads();

    int cur = 0;
    for (int k0 = 0; k0 < K; k0 += 32) {
        const short* Ac = As + cur * 64 * 32;
        const short* Bc = Bs + cur * 64 * 32;
        short8 af[4], bfr[4];
        #pragma unroll
        for (int t = 0; t < 4; t++) {
            af[t]  = *(const short8*)&Ac[(t * 16 + fr) * 32 + fk];
            bfr[t] = *(const short8*)&Bc[(t * 16 + fr) * 32 + fk];
        }
        if (k0 + 32 < K) {
            const int nb = cur ^ 1;
            #pragma unroll
            for (int r = 0; r < 4; r++) {
                async16(gA + (size_t)(r * 16) * K + k0 + 32, lA + (nb * 64 + r * 16) * 32);
                async16(gB + (size_t)(r * 16) * K + k0 + 32, lB + (nb * 64 + r * 16) * 32);
            }
        }
        #pragma unroll
        for (int i = 0; i < 4; i++)
            #pragma unroll
            for (int j = 0; j < 4; j++)
                acc[i][j] = __builtin_amdgcn_mfma_f32_16x16x32_bf16(
                    af[i], bfr[j], acc[i][j], 0, 0, 0);
        __syncthreads();
        cur ^= 1;
    }

    // C/D layout: col = lane&15, row = (lane>>4)*4 + r
    const int crow = row0 + (lane >> 4) * 4;
    const int ccol = col0 + (lane & 15);
    #pragma unroll
    for (int i = 0; i < 4; i++) {
        #pragma unroll
        for (int j = 0; j < 4; j++) {
            const int c = ccol + j * 16;
            #pragma unroll
            for (int r = 0; r < 4; r++) {
                float v = acc[i][j][r];
                if (EP == 1) v = softplusf(v + bias[c]);
                else if (EP == 2) v = siluf(v + bias[c]);
                else if (EP == 3) v = siluf(v);
                const size_t idx = cbase + (size_t)(crow + i * 16 + r) * N + c;
                if (FIN) v = siluf(Sadd[idx] + v);
                if (OUT16) ((unsigned short*)Cout)[idx] = f2bf(v);
                else       ((float*)Cout)[idx] = v;
            }
        }
    }
}

// ---------------------------------------------------------------------------
// Both Wcomb = Wdt(1024x64) @ Wx[:64](64x1024) in one dispatch (z = layer).
// ---------------------------------------------------------------------------
__global__ __launch_bounds__(256) void gemm_nn_wcomb(
    const float* __restrict__ Wdt1, const float* __restrict__ Wx1,
    unsigned short* __restrict__ C1,
    const float* __restrict__ Wdt2, const float* __restrict__ Wx2,
    unsigned short* __restrict__ C2)
{
    const float* Wdt = blockIdx.z ? Wdt2 : Wdt1;
    const float* Wx  = blockIdx.z ? Wx2  : Wx1;
    unsigned short* C16 = blockIdx.z ? C2 : C1;

    __shared__ float Asf[16][64];
    __shared__ float Bsf[16][64];

    const int tid = threadIdx.x;
    const int tx = tid & 15;
    const int ty = tid >> 4;
    const int row0 = blockIdx.y * 64;
    const int col0 = blockIdx.x * 64;
    const int lrow = tid >> 2;
    const int lcol = (tid & 3) * 4;
    const int bk = tid >> 4;
    const int bn = (tid & 15) * 4;

    float acc[4][4] = {};

    for (int k0 = 0; k0 < 64; k0 += 16) {
        const float4 av = *(const float4*)(Wdt + (size_t)(row0 + lrow) * 64 + k0 + lcol);
        Asf[lcol + 0][lrow] = av.x;
        Asf[lcol + 1][lrow] = av.y;
        Asf[lcol + 2][lrow] = av.z;
        Asf[lcol + 3][lrow] = av.w;
        *(float4*)&Bsf[bk][bn] = *(const float4*)(Wx + (size_t)(k0 + bk) * 1024 + col0 + bn);
        __syncthreads();

        #pragma unroll
        for (int kk = 0; kk < 16; kk++) {
            const float4 a = *(const float4*)&Asf[kk][ty * 4];
            const float4 b = *(const float4*)&Bsf[kk][tx * 4];
            const float af[4] = {a.x, a.y, a.z, a.w};
            const float bfv[4] = {b.x, b.y, b.z, b.w};
            #pragma unroll
            for (int i = 0; i < 4; i++)
                #pragma unroll
                for (int j = 0; j < 4; j++)
                    acc[i][j] = fmaf(af[i], bfv[j], acc[i][j]);
        }
        __syncthreads();
    }

    #pragma unroll
    for (int i = 0; i < 4; i++) {
        const int r = row0 + ty * 4 + i;
        #pragma unroll
        for (int j = 0; j < 4; j++)
            C16[(size_t)r * 1024 + col0 + tx * 4 + j] = f2bf(acc[i][j]);
    }
}

// ---------------------------------------------------------------------------
// Depthwise causal conv (k=4) + bias + SiLU, fused B/C projection.
// xz now bf16. Each thread handles 4 consecutive d. Writes xi16 + bc.
// ---------------------------------------------------------------------------
__global__ __launch_bounds__(256) void conv_silu_bc(
    const unsigned short* __restrict__ xz16,
    const float* __restrict__ convw,
    const float* __restrict__ convb,
    const float* __restrict__ Wx,     // (68, 1024): rows 64..67 = B0,B1,C0,C1
    unsigned short* __restrict__ xi16,
    float* __restrict__ bc)           // (4096, 4)
{
    __shared__ float redc[4][4];
    const int r = blockIdx.x;
    const int l = r & (LSEQ - 1);
    const int tid = threadIdx.x;
    const int d0 = tid * 4;

    ushortx4 x0 = *(const ushortx4*)(xz16 + (size_t)r * TWO_DI + d0);
    ushortx4 x1 = {0,0,0,0}, x2 = {0,0,0,0}, x3 = {0,0,0,0};
    if (l >= 1) x1 = *(const ushortx4*)(xz16 + (size_t)(r - 1) * TWO_DI + d0);
    if (l >= 2) x2 = *(const ushortx4*)(xz16 + (size_t)(r - 2) * TWO_DI + d0);
    if (l >= 3) x3 = *(const ushortx4*)(xz16 + (size_t)(r - 3) * TWO_DI + d0);

    float p0 = 0.f, p1 = 0.f, p2 = 0.f, p3 = 0.f;
    ushortx4 outv;
    #pragma unroll
    for (int j = 0; j < 4; j++) {
        const int d = d0 + j;
        const float4 w = *(const float4*)(convw + d * 4);  // w0,w1,w2,w3
        float acc = w.w * bf2f(x0[j]);
        acc = fmaf(w.z, bf2f(x1[j]), acc);
        acc = fmaf(w.y, bf2f(x2[j]), acc);
        acc = fmaf(w.x, bf2f(x3[j]), acc);
        const float v = siluf(acc + convb[d]);
        outv[j] = f2bf(v);
        p0 = fmaf(v, Wx[64 * 1024 + d], p0);
        p1 = fmaf(v, Wx[65 * 1024 + d], p1);
        p2 = fmaf(v, Wx[66 * 1024 + d], p2);
        p3 = fmaf(v, Wx[67 * 1024 + d], p3);
    }
    *(ushortx4*)(xi16 + (size_t)r * DI + d0) = outv;

    #pragma unroll
    for (int o = 32; o; o >>= 1) {
        p0 += __shfl_down(p0, o, 64);
        p1 += __shfl_down(p1, o, 64);
        p2 += __shfl_down(p2, o, 64);
        p3 += __shfl_down(p3, o, 64);
    }
    const int w = tid >> 6, lane = tid & 63;
    if (lane == 0) {
        redc[w][0] = p0; redc[w][1] = p1; redc[w][2] = p2; redc[w][3] = p3;
    }
    __syncthreads();
    if (tid < 4)
        bc[r * 4 + tid] = redc[0][tid] + redc[1][tid] + redc[2][tid] + redc[3][tid];
}

// ---------------------------------------------------------------------------
// Chunked selective scan (n=2). NCH chunks of CHL steps.
// ---------------------------------------------------------------------------
__global__ __launch_bounds__(256) void scan_part1(
    const unsigned short* __restrict__ dt16,
    const unsigned short* __restrict__ xi16,
    const float* __restrict__ bc,
    const float* __restrict__ Alog,
    float4* __restrict__ hc)          // (B, NCH, DI)
{
    const int d  = blockIdx.x * 256 + threadIdx.x;
    const int b  = blockIdx.y;
    const int ch = blockIdx.z;
    const float A0 = -__expf(Alog[d * 2 + 0]);
    const float A1 = -__expf(Alog[d * 2 + 1]);
    float h0 = 0.f, h1 = 0.f, p0 = 1.f, p1 = 1.f;
    const int r0 = b * LSEQ + ch * CHL;
    #pragma unroll 4
    for (int l = 0; l < CHL; l++) {
        const int r = r0 + l;
        const float dtv = bf2f(dt16[(size_t)r * DI + d]);
        const float xiv = bf2f(xi16[(size_t)r * DI + d]);
        const float4 bcv = *(const float4*)(bc + r * 4);
        const float e0 = __expf(dtv * A0);
        const float e1 = __expf(dtv * A1);
        const float dbx = dtv * xiv;
        h0 = fmaf(e0, h0, dbx * bcv.x);
        h1 = fmaf(e1, h1, dbx * bcv.y);
        p0 *= e0; p1 *= e1;
    }
    hc[(size_t)(b * NCH + ch) * DI + d] = make_float4(h0, h1, p0, p1);
}

__global__ __launch_bounds__(256) void scan_carry(
    const float4* __restrict__ hc,
    float2* __restrict__ ci)          // (B, NCH, DI)
{
    const int d = blockIdx.x * 256 + threadIdx.x;
    const int b = blockIdx.y;
    float c0 = 0.f, c1 = 0.f;
    #pragma unroll
    for (int ch = 0; ch < NCH; ch++) {
        const size_t idx = (size_t)(b * NCH + ch) * DI + d;
        const float4 v = hc[idx];
        ci[idx] = make_float2(c0, c1);
        c0 = fmaf(v.z, c0, v.x);
        c1 = fmaf(v.w, c1, v.y);
    }
}

__global__ __launch_bounds__(256) void scan_part2(
    const unsigned short* __restrict__ dt16,
    const unsigned short* __restrict__ xi16,
    const unsigned short* __restrict__ xz16,  // z = cols [1024,2048)
    const float* __restrict__ bc,
    const float* __restrict__ Alog,
    const float* __restrict__ Dp,
    const float2* __restrict__ ci,
    unsigned short* __restrict__ yg16)
{
    const int d  = blockIdx.x * 256 + threadIdx.x;
    const int b  = blockIdx.y;
    const int ch = blockIdx.z;
    const float A0 = -__expf(Alog[d * 2 + 0]);
    const float A1 = -__expf(Alog[d * 2 + 1]);
    const float Dv = Dp[d];
    const float2 c = ci[(size_t)(b * NCH + ch) * DI + d];
    float h0 = c.x, h1 = c.y;
    const int r0 = b * LSEQ + ch * CHL;
    #pragma unroll 4
    for (int l = 0; l < CHL; l++) {
        const int r = r0 + l;
        const float dtv = bf2f(dt16[(size_t)r * DI + d]);
        const float xiv = bf2f(xi16[(size_t)r * DI + d]);
        const float4 bcv = *(const float4*)(bc + r * 4);
        const float zv = bf2f(xz16[(size_t)r * TWO_DI + DI + d]);
        const float e0 = __expf(dtv * A0);
        const float e1 = __expf(dtv * A1);
        const float dbx = dtv * xiv;
        h0 = fmaf(e0, h0, dbx * bcv.x);
        h1 = fmaf(e1, h1, dbx * bcv.y);
        const float y = fmaf(h0, bcv.z, fmaf(h1, bcv.w, Dv * xiv));
        yg16[(size_t)r * DI + d] = f2bf(y * siluf(zv));
    }
}

// ---------------------------------------------------------------------------
// LayerNorm over last dim (1024), in-place.
// ---------------------------------------------------------------------------
__global__ __launch_bounds__(256) void ln_kernel(
    float* __restrict__ s,
    const float* __restrict__ g,
    const float* __restrict__ bb)
{
    __shared__ float red[8];
    const size_t base = (size_t)blockIdx.x * DM;
    const int t = threadIdx.x;
    float x0 = s[base + t];
    float x1 = s[base + t + 256];
    float x2 = s[base + t + 512];
    float x3 = s[base + t + 768];
    float sum = x0 + x1 + x2 + x3;
    #pragma unroll
    for (int o = 32; o; o >>= 1) sum += __shfl_down(sum, o, 64);
    const int w = t >> 6, lane = t & 63;
    if (lane == 0) red[w] = sum;
    __syncthreads();
    const float m = (red[0] + red[1] + red[2] + red[3]) * (1.0f / 1024.0f);
    const float d0 = x0 - m, d1 = x1 - m, d2 = x2 - m, d3 = x3 - m;
    float ss = d0 * d0 + d1 * d1 + d2 * d2 + d3 * d3;
    #pragma unroll
    for (int o = 32; o; o >>= 1) ss += __shfl_down(ss, o, 64);
    if (lane == 0) red[4 + w] = ss;
    __syncthreads();
    const float var = (red[4] + red[5] + red[6] + red[7]) * (1.0f / 1024.0f);
    const float inv = rsqrtf(var + 1e-5f);
    s[base + t]       = d0 * inv * g[t]       + bb[t];
    s[base + t + 256] = d1 * inv * g[t + 256] + bb[t + 256];
    s[base + t + 512] = d2 * inv * g[t + 512] + bb[t + 512];
    s[base + t + 768] = d3 * inv * g[t + 768] + bb[t + 768];
}

// ---------------------------------------------------------------------------
// transpose + cast fp32 (b,256c,1024s) -> bf16 (b,1024s,256c)
// ---------------------------------------------------------------------------
__global__ __launch_bounds__(256) void transpose_cast(
    const float* __restrict__ in, unsigned short* __restrict__ out)
{
    __shared__ float tile[32][33];
    const int b = blockIdx.z;
    const int c0 = blockIdx.y * 32;
    const int s0 = blockIdx.x * 32;
    const int tx = threadIdx.x & 31;
    const int ty = threadIdx.x >> 5;   // 0..7
    const size_t ib = (size_t)b * 256 * 1024;
    const size_t ob = (size_t)b * 1024 * 256;
    #pragma unroll
    for (int i = 0; i < 4; i++)
        tile[tx][ty + i * 8] = in[ib + (size_t)(c0 + ty + i * 8) * 1024 + s0 + tx];
    __syncthreads();
    #pragma unroll
    for (int i = 0; i < 4; i++)
        out[ob + (size_t)(s0 + ty + i * 8) * 256 + c0 + tx] = f2bf(tile[ty + i * 8][tx]);
}

// bf16 in -> bf16 out transpose (same shapes)
__global__ __launch_bounds__(256) void transpose16(
    const unsigned short* __restrict__ in, unsigned short* __restrict__ out)
{
    __shared__ unsigned short tile[32][34];
    const int b = blockIdx.z;
    const int c0 = blockIdx.y * 32;
    const int s0 = blockIdx.x * 32;
    const int tx = threadIdx.x & 31;
    const int ty = threadIdx.x >> 5;
    const size_t ib = (size_t)b * 256 * 1024;
    const size_t ob = (size_t)b * 1024 * 256;
    #pragma unroll
    for (int i = 0; i < 4; i++)
        tile[tx][ty + i * 8] = in[ib + (size_t)(c0 + ty + i * 8) * 1024 + s0 + tx];
    __syncthreads();
    #pragma unroll
    for (int i = 0; i < 4; i++)
        out[ob + (size_t)(s0 + ty + i * 8) * 256 + c0 + tx] = tile[ty + i * 8][tx];
}

// ---------------------------------------------------------------------------
extern "C" void kernel_launch(void* const* d_in, const int* in_sizes, int n_in,
                              void* d_out, int out_size, void* d_ws, size_t ws_size,
                              hipStream_t stream)
{
    const float* x        = (const float*)d_in[0];
    const float* m1_Win   = (const float*)d_in[1];
    const float* m1_convw = (const float*)d_in[2];
    const float* m1_convb = (const float*)d_in[3];
    const float* m1_Wx    = (const float*)d_in[4];
    const float* m1_Wdt   = (const float*)d_in[5];
    const float* m1_bdt   = (const float*)d_in[6];
    const float* m1_Alog  = (const float*)d_in[7];
    const float* m1_D     = (const float*)d_in[8];
    const float* m1_Wout  = (const float*)d_in[9];
    const float* m2_Win   = (const float*)d_in[10];
    const float* m2_convw = (const float*)d_in[11];
    const float* m2_convb = (const float*)d_in[12];
    const float* m2_Wx    = (const float*)d_in[13];
    const float* m2_Wdt   = (const float*)d_in[14];
    const float* m2_bdt   = (const float*)d_in[15];
    const float* m2_Alog  = (const float*)d_in[16];
    const float* m2_D     = (const float*)d_in[17];
    const float* m2_Wout  = (const float*)d_in[18];
    const float* ln1_g    = (const float*)d_in[19];
    const float* ln1_b    = (const float*)d_in[20];
    const float* ln2_g    = (const float*)d_in[21];
    const float* ln2_b    = (const float*)d_in[22];
    const float* W_mid    = (const float*)d_in[23];
    const float* W_spa    = (const float*)d_in[24];
    const float* b_spa    = (const float*)d_in[25];
    const float* W_res    = (const float*)d_in[26];

    float* ws = (float*)d_ws;
    size_t off = 0;
    float* buf_s   = ws + off; off += (size_t)NROWS * DI;              // 16 MB
    float* buf_bc  = ws + off; off += (size_t)NROWS * 4;
    float4* buf_hc = (float4*)(ws + off); off += (size_t)BATCH * NCH * DI * 4;
    float2* buf_ci = (float2*)(ws + off); off += (size_t)BATCH * NCH * DI * 2;
    unsigned short* xz16   = (unsigned short*)(ws + off); off += (size_t)NROWS * TWO_DI / 2; // 16 MB
    unsigned short* bx     = (unsigned short*)(ws + off); off += (size_t)NROWS * DI / 2;
    unsigned short* xi16   = (unsigned short*)(ws + off); off += (size_t)NROWS * DI / 2;
    unsigned short* yg16   = (unsigned short*)(ws + off); off += (size_t)NROWS * DI / 2;
    unsigned short* sT16   = (unsigned short*)(ws + off); off += (size_t)NROWS * DI / 2;
    unsigned short* dt16   = (unsigned short*)(ws + off); off += (size_t)NROWS * DI / 2;
    unsigned short* res16  = (unsigned short*)(ws + off); off += (size_t)NROWS * DI / 2;
    unsigned short* win1   = (unsigned short*)(ws + off); off += (size_t)TWO_DI * DM / 2;
    unsigned short* wout1  = (unsigned short*)(ws + off); off += (size_t)DM * DI / 2;
    unsigned short* win2   = (unsigned short*)(ws + off); off += (size_t)TWO_DI * DM / 2;
    unsigned short* wout2  = (unsigned short*)(ws + off); off += (size_t)DM * DI / 2;
    unsigned short* wspa16 = (unsigned short*)(ws + off); off += (size_t)DM * DM / 2;
    unsigned short* wcomb1 = (unsigned short*)(ws + off); off += (size_t)DI * DI / 2;
    unsigned short* wcomb2 = (unsigned short*)(ws + off); off += (size_t)DI * DI / 2;
    unsigned short* wmid16 = (unsigned short*)(ws + off); off += (size_t)LSEQ * LSEQ / 2;
    unsigned short* wres16 = (unsigned short*)(ws + off); off += (size_t)LSEQ * LSEQ / 2;
    unsigned short* t16  = yg16;   // mix1 out / mamba2 in (lifetimes disjoint)
    unsigned short* rT16 = sT16;   // residual transpose after mix1 consumed sT16
    (void)ws_size; (void)n_in; (void)in_sizes; (void)out_size;

    const dim3 blk(256);
    const dim3 blk64(64);

    // ---- all input casts in one dispatch ----
    cast8<<<dim3(11392), blk, 0, stream>>>(
        x, bx, m1_Win, win1, m1_Wout, wout1, m2_Win, win2, m2_Wout, wout2,
        W_spa, wspa16, W_mid, wmid16, W_res, wres16);
    // ---- both Wcomb = Wdt @ Wx[:64] ----
    gemm_nn_wcomb<<<dim3(16, 16, 2), blk, 0, stream>>>(
        m1_Wdt, m1_Wx, wcomb1, m2_Wdt, m2_Wx, wcomb2);

    auto mamba = [&](const unsigned short* inp16, const unsigned short* win16,
                     const unsigned short* wcomb16, const unsigned short* wout16,
                     const float* convw, const float* convb, const float* Wx,
                     const float* bdt, const float* Alog, const float* Dp,
                     float* out_buf) {
        // xz16 = bf16(inp @ Win.T) : (4096,2048)  [2048 blocks]
        gemm1w<0, 1, 0, 0><<<dim3(TWO_DI / 64, NROWS / 64), blk64, 0, stream>>>(
            (const short*)inp16, (const short*)win16, nullptr, nullptr,
            (void*)xz16, NROWS, TWO_DI, DM);
        // conv + silu + fused B/C projection -> xi16, bc
        conv_silu_bc<<<dim3(NROWS), blk, 0, stream>>>(
            xz16, convw, convb, Wx, xi16, buf_bc);
        // dt16 = bf16(softplus(xi @ Wcomb.T + bdt))  [1024 blocks]
        gemm1w<1, 1, 0, 0><<<dim3(DI / 64, NROWS / 64), blk64, 0, stream>>>(
            (const short*)xi16, (const short*)wcomb16, bdt, nullptr,
            (void*)dt16, NROWS, DI, DI);
        // chunked scan -> yg16
        scan_part1<<<dim3(DI / 256, BATCH, NCH), blk, 0, stream>>>(
            dt16, xi16, buf_bc, Alog, buf_hc);
        scan_carry<<<dim3(DI / 256, BATCH), blk, 0, stream>>>(buf_hc, buf_ci);
        scan_part2<<<dim3(DI / 256, BATCH, NCH), blk, 0, stream>>>(
            dt16, xi16, xz16, buf_bc, Alog, Dp, buf_ci, yg16);
        // out = yg @ Wout.T : (4096,1024) fp32  [1024 blocks]
        gemm1w<0, 0, 0, 0><<<dim3(DM / 64, NROWS / 64), blk64, 0, stream>>>(
            (const short*)yg16, (const short*)wout16, nullptr, nullptr,
            (void*)out_buf, NROWS, DM, DI);
    };

    // ---- Mamba 1 + LN1 ----
    mamba(bx, win1, wcomb1, wout1, m1_convw, m1_convb, m1_Wx, m1_bdt,
          m1_Alog, m1_D, buf_s);
    ln_kernel<<<dim3(NROWS), blk, 0, stream>>>(buf_s, ln1_g, ln1_b);

    // ---- channel mix 1: t16[b] = bf16(silu(W_mid @ s[b])) ----
    transpose_cast<<<dim3(32, 8, BATCH), blk, 0, stream>>>(buf_s, sT16);
    gemm1w<3, 1, 1, 0><<<dim3(DM / 64, LSEQ / 64, BATCH), blk64, 0, stream>>>(
        (const short*)wmid16, (const short*)sT16, nullptr, nullptr,
        (void*)t16, LSEQ, DM, LSEQ);

    // ---- Mamba 2 + LN2 ----
    mamba(t16, win2, wcomb2, wout2, m2_convw, m2_convb, m2_Wx, m2_bdt,
          m2_Alog, m2_D, buf_s);
    ln_kernel<<<dim3(NROWS), blk, 0, stream>>>(buf_s, ln2_g, ln2_b);

    // ---- residual path: res16 = bf16(silu(x @ W_spa.T + b_spa)) ----
    gemm1w<2, 1, 0, 0><<<dim3(DM / 64, NROWS / 64), blk64, 0, stream>>>(
        (const short*)bx, (const short*)wspa16, b_spa, nullptr,
        (void*)res16, NROWS, DM, DM);
    transpose16<<<dim3(32, 8, BATCH), blk, 0, stream>>>(res16, rT16);
    // mix2 + final fuse: d_out = silu(s + silu(W_res @ r))
    gemm1w<3, 0, 1, 1><<<dim3(DM / 64, LSEQ / 64, BATCH), blk64, 0, stream>>>(
        (const short*)wres16, (const short*)rT16, nullptr, buf_s,
        d_out, LSEQ, DM, LSEQ);
}

// Round 8
// 463.381 us; speedup vs baseline: 1.0197x; 1.0197x over previous
//
#include <hip/hip_runtime.h>
#include <math.h>

// Problem constants (B=16, L=C=256 scan axis, dm=di=1024, n=2, dtr=64, k=4)
#define BATCH 16
#define LSEQ  256
#define DM    1024
#define DI    1024
#define NROWS (BATCH*LSEQ)   // 4096
#define DTR   64
#define TWO_DI 2048
#define NCH   16             // scan chunks
#define CHL   16             // chunk length (NCH*CHL == LSEQ)

typedef __attribute__((ext_vector_type(8))) short short8;
typedef __attribute__((ext_vector_type(4))) float floatx4;
typedef __attribute__((ext_vector_type(4))) unsigned short ushortx4;

__device__ __forceinline__ float siluf(float x) {
    return x / (1.0f + __expf(-x));
}
__device__ __forceinline__ float softplusf(float x) {
    return fmaxf(x, 0.0f) + log1pf(__expf(-fabsf(x)));
}
// fp32 -> bf16 (RNE), raw bits
__device__ __forceinline__ unsigned short f2bf(float f) {
    unsigned int u = __float_as_uint(f);
    u += 0x7fffu + ((u >> 16) & 1u);
    return (unsigned short)(u >> 16);
}
__device__ __forceinline__ float bf2f(unsigned short s) {
    return __uint_as_float(((unsigned int)s) << 16);
}
// async global->LDS, 16B per lane; LDS dest = wave-uniform base + lane*16
__device__ __forceinline__ void async16(const short* g, short* l) {
    __builtin_amdgcn_global_load_lds(
        (const __attribute__((address_space(1))) unsigned int*)g,
        (__attribute__((address_space(3))) unsigned int*)l,
        16, 0, 0);
}
// per-wave wait for ALL outstanding vmem (incl. global_load_lds) -- no barrier.
// simm16: vmcnt=0, expcnt=7 (ignore), lgkmcnt=15 (ignore) -> 0x0F70.
__device__ __forceinline__ void wait_vm0() {
    __builtin_amdgcn_s_waitcnt(0x0F70);
}

// ---------------------------------------------------------------------------
// cast8: all fp32->bf16 input casts in ONE dispatch. 1024 elts per block.
// ---------------------------------------------------------------------------
__global__ __launch_bounds__(256) void cast8(
    const float* __restrict__ x,    unsigned short* __restrict__ ox,
    const float* __restrict__ w1i,  unsigned short* __restrict__ o1i,
    const float* __restrict__ w1o,  unsigned short* __restrict__ o1o,
    const float* __restrict__ w2i,  unsigned short* __restrict__ o2i,
    const float* __restrict__ w2o,  unsigned short* __restrict__ o2o,
    const float* __restrict__ wsp,  unsigned short* __restrict__ osp,
    const float* __restrict__ wmd,  unsigned short* __restrict__ omd,
    const float* __restrict__ wrs,  unsigned short* __restrict__ ors)
{
    const int b = blockIdx.x;
    const float* in; unsigned short* out; int base;
    if      (b <  4096) { in = x;   out = ox;  base = 0; }
    else if (b <  6144) { in = w1i; out = o1i; base = 4096; }
    else if (b <  7168) { in = w1o; out = o1o; base = 6144; }
    else if (b <  9216) { in = w2i; out = o2i; base = 7168; }
    else if (b < 10240) { in = w2o; out = o2o; base = 9216; }
    else if (b < 11264) { in = wsp; out = osp; base = 10240; }
    else if (b < 11328) { in = wmd; out = omd; base = 11264; }
    else                { in = wrs; out = ors; base = 11328; }
    const size_t i = ((size_t)(b - base) * 256 + threadIdx.x) * 4;
    const float4 v = *(const float4*)(in + i);
    union { unsigned short s[4]; unsigned long long u; } p;
    p.s[0] = f2bf(v.x); p.s[1] = f2bf(v.y);
    p.s[2] = f2bf(v.z); p.s[3] = f2bf(v.w);
    *(unsigned long long*)(out + i) = p.u;
}

// ---------------------------------------------------------------------------
// Split-K bf16 MFMA GEMM (nt): C[M,N] = A[M,K] @ W[N,K]^T.
// 256 thr = 4 waves; 64x64 tile; each wave independently does a K/4 slice
// with private 8 KB single-buffer LDS staging and NO barrier in the K-loop.
// Per-wave s_waitcnt vmcnt(0) (wait_vm0) orders global_load_lds -> ds_read;
// waves stay decoupled, 20 waves/CU nominal at 1024+ blocks.
// End: two-phase LDS reduction of the 4 fp32 partials + fused epilogue.
// EP: 0=none, 1=softplus(v+bias[c]), 2=silu(v+bias[c]), 3=silu(v)
// OUT16: bf16 out. BATW: W,C batched by blockIdx.z. FIN: v=silu(Sadd+v').
// Requires M%64==0, N%64==0, (K/4)%32==0.
// ---------------------------------------------------------------------------
template <int EP, int OUT16, int BATW, int FIN>
__global__ __launch_bounds__(256) void gemm_sk(
    const short* __restrict__ A,
    const short* __restrict__ W,
    const float* __restrict__ bias,
    const float* __restrict__ Sadd,
    void* __restrict__ Cout,
    int M, int N, int K)
{
    __shared__ float fl[8192];   // 32 KB: staging (4 x 8 KB) then reduction (4 x 8 KB)

    const int bz = BATW ? blockIdx.z : 0;
    const short* Wb = W + (size_t)bz * N * K;
    const size_t cbase = (size_t)bz * M * N;

    const int tid  = threadIdx.x;
    const int w    = tid >> 6;
    const int lane = tid & 63;
    const int row0 = blockIdx.y * 64;
    const int col0 = blockIdx.x * 64;

    const int Kw  = K >> 2;        // per-wave K slice
    const int wk0 = w * Kw;

    const int srow  = lane >> 2;         // 0..15
    const int skoff = (lane & 3) * 8;    // k elts
    const short* gA = A  + (size_t)(row0 + srow) * K + wk0 + skoff;
    const short* gB = Wb + (size_t)(col0 + srow) * K + wk0 + skoff;
    short* st = (short*)fl + w * 4096;   // this wave's 8 KB staging region
    short* lA = st + lane * 8;           // A at +0 (64x32), B at +2048
    short* lB = lA + 2048;

    const int fr = lane & 15;
    const int fk = (lane >> 4) * 8;
    const int q  = lane >> 4;

    floatx4 acc[4][4] = {};

    for (int kk = 0; kk < Kw; kk += 32) {
        #pragma unroll
        for (int r = 0; r < 4; r++) {
            async16(gA + (size_t)(r * 16) * K + kk, lA + r * 512);
            async16(gB + (size_t)(r * 16) * K + kk, lB + r * 512);
        }
        wait_vm0();   // per-wave: DMA-to-LDS complete before ds_read (NO barrier)
        short8 af[4], bf[4];
        #pragma unroll
        for (int t = 0; t < 4; t++) {
            af[t] = *(const short8*)&st[(t * 16 + fr) * 32 + fk];
            bf[t] = *(const short8*)&st[2048 + (t * 16 + fr) * 32 + fk];
        }
        #pragma unroll
        for (int i = 0; i < 4; i++)
            #pragma unroll
            for (int j = 0; j < 4; j++)
                acc[i][j] = __builtin_amdgcn_mfma_f32_16x16x32_bf16(
                    af[i], bf[j], acc[i][j], 0, 0, 0);
    }

    // two-phase cross-wave reduction (rows [0,32) then [32,64))
    #pragma unroll
    for (int p = 0; p < 2; p++) {
        __syncthreads();   // phase 0: all K-loops done; phase 1: reduce reads done
        #pragma unroll
        for (int i = 0; i < 2; i++) {        // global acc i = 2p + i
            #pragma unroll
            for (int j = 0; j < 4; j++) {
                #pragma unroll
                for (int r = 0; r < 4; r++) {
                    const int rloc = i * 16 + q * 4 + r;   // 0..31
                    const int col  = j * 16 + fr;
                    fl[w * 2048 + rloc * 64 + col] = acc[2 * p + i][j][r];
                }
            }
        }
        __syncthreads();
        #pragma unroll
        for (int v = 0; v < 2; v++) {
            const int f = tid * 2 + v;       // 0..511 float4s of 32x64 tile
            const int rloc = f >> 4;
            const int cb = (f & 15) * 4;
            const float* p0 = &fl[rloc * 64 + cb];
            const float4 s0 = *(const float4*)(p0);
            const float4 s1 = *(const float4*)(p0 + 2048);
            const float4 s2 = *(const float4*)(p0 + 4096);
            const float4 s3 = *(const float4*)(p0 + 6144);
            float sv[4] = { s0.x + s1.x + s2.x + s3.x,
                            s0.y + s1.y + s2.y + s3.y,
                            s0.z + s1.z + s2.z + s3.z,
                            s0.w + s1.w + s2.w + s3.w };
            const int grow = row0 + p * 32 + rloc;
            #pragma unroll
            for (int e = 0; e < 4; e++) {
                const int c = col0 + cb + e;
                float vv = sv[e];
                if (EP == 1) vv = softplusf(vv + bias[c]);
                else if (EP == 2) vv = siluf(vv + bias[c]);
                else if (EP == 3) vv = siluf(vv);
                const size_t idx = cbase + (size_t)grow * N + c;
                if (FIN) vv = siluf(Sadd[idx] + vv);
                if (OUT16) ((unsigned short*)Cout)[idx] = f2bf(vv);
                else       ((float*)Cout)[idx] = vv;
            }
        }
    }
}

// ---------------------------------------------------------------------------
// Both Wcomb = Wdt(1024x64) @ Wx[:64](64x1024) in one dispatch (z = layer).
// ---------------------------------------------------------------------------
__global__ __launch_bounds__(256) void gemm_nn_wcomb(
    const float* __restrict__ Wdt1, const float* __restrict__ Wx1,
    unsigned short* __restrict__ C1,
    const float* __restrict__ Wdt2, const float* __restrict__ Wx2,
    unsigned short* __restrict__ C2)
{
    const float* Wdt = blockIdx.z ? Wdt2 : Wdt1;
    const float* Wx  = blockIdx.z ? Wx2  : Wx1;
    unsigned short* C16 = blockIdx.z ? C2 : C1;

    __shared__ float Asf[16][64];
    __shared__ float Bsf[16][64];

    const int tid = threadIdx.x;
    const int tx = tid & 15;
    const int ty = tid >> 4;
    const int row0 = blockIdx.y * 64;
    const int col0 = blockIdx.x * 64;
    const int lrow = tid >> 2;
    const int lcol = (tid & 3) * 4;
    const int bk = tid >> 4;
    const int bn = (tid & 15) * 4;

    float acc[4][4] = {};

    for (int k0 = 0; k0 < 64; k0 += 16) {
        const float4 av = *(const float4*)(Wdt + (size_t)(row0 + lrow) * 64 + k0 + lcol);
        Asf[lcol + 0][lrow] = av.x;
        Asf[lcol + 1][lrow] = av.y;
        Asf[lcol + 2][lrow] = av.z;
        Asf[lcol + 3][lrow] = av.w;
        *(float4*)&Bsf[bk][bn] = *(const float4*)(Wx + (size_t)(k0 + bk) * 1024 + col0 + bn);
        __syncthreads();

        #pragma unroll
        for (int kk = 0; kk < 16; kk++) {
            const float4 a = *(const float4*)&Asf[kk][ty * 4];
            const float4 b = *(const float4*)&Bsf[kk][tx * 4];
            const float af[4] = {a.x, a.y, a.z, a.w};
            const float bfv[4] = {b.x, b.y, b.z, b.w};
            #pragma unroll
            for (int i = 0; i < 4; i++)
                #pragma unroll
                for (int j = 0; j < 4; j++)
                    acc[i][j] = fmaf(af[i], bfv[j], acc[i][j]);
        }
        __syncthreads();
    }

    #pragma unroll
    for (int i = 0; i < 4; i++) {
        const int r = row0 + ty * 4 + i;
        #pragma unroll
        for (int j = 0; j < 4; j++)
            C16[(size_t)r * 1024 + col0 + tx * 4 + j] = f2bf(acc[i][j]);
    }
}

// ---------------------------------------------------------------------------
// Depthwise causal conv (k=4) + bias + SiLU, fused B/C projection.
// ---------------------------------------------------------------------------
__global__ __launch_bounds__(256) void conv_silu_bc(
    const unsigned short* __restrict__ xz16,
    const float* __restrict__ convw,
    const float* __restrict__ convb,
    const float* __restrict__ Wx,     // (68, 1024): rows 64..67 = B0,B1,C0,C1
    unsigned short* __restrict__ xi16,
    float* __restrict__ bc)           // (4096, 4)
{
    __shared__ float redc[4][4];
    const int r = blockIdx.x;
    const int l = r & (LSEQ - 1);
    const int tid = threadIdx.x;
    const int d0 = tid * 4;

    ushortx4 x0 = *(const ushortx4*)(xz16 + (size_t)r * TWO_DI + d0);
    ushortx4 x1 = {0,0,0,0}, x2 = {0,0,0,0}, x3 = {0,0,0,0};
    if (l >= 1) x1 = *(const ushortx4*)(xz16 + (size_t)(r - 1) * TWO_DI + d0);
    if (l >= 2) x2 = *(const ushortx4*)(xz16 + (size_t)(r - 2) * TWO_DI + d0);
    if (l >= 3) x3 = *(const ushortx4*)(xz16 + (size_t)(r - 3) * TWO_DI + d0);

    float p0 = 0.f, p1 = 0.f, p2 = 0.f, p3 = 0.f;
    ushortx4 outv;
    #pragma unroll
    for (int j = 0; j < 4; j++) {
        const int d = d0 + j;
        const float4 w = *(const float4*)(convw + d * 4);
        float acc = w.w * bf2f(x0[j]);
        acc = fmaf(w.z, bf2f(x1[j]), acc);
        acc = fmaf(w.y, bf2f(x2[j]), acc);
        acc = fmaf(w.x, bf2f(x3[j]), acc);
        const float v = siluf(acc + convb[d]);
        outv[j] = f2bf(v);
        p0 = fmaf(v, Wx[64 * 1024 + d], p0);
        p1 = fmaf(v, Wx[65 * 1024 + d], p1);
        p2 = fmaf(v, Wx[66 * 1024 + d], p2);
        p3 = fmaf(v, Wx[67 * 1024 + d], p3);
    }
    *(ushortx4*)(xi16 + (size_t)r * DI + d0) = outv;

    #pragma unroll
    for (int o = 32; o; o >>= 1) {
        p0 += __shfl_down(p0, o, 64);
        p1 += __shfl_down(p1, o, 64);
        p2 += __shfl_down(p2, o, 64);
        p3 += __shfl_down(p3, o, 64);
    }
    const int w = tid >> 6, lane = tid & 63;
    if (lane == 0) {
        redc[w][0] = p0; redc[w][1] = p1; redc[w][2] = p2; redc[w][3] = p3;
    }
    __syncthreads();
    if (tid < 4)
        bc[r * 4 + tid] = redc[0][tid] + redc[1][tid] + redc[2][tid] + redc[3][tid];
}

// ---------------------------------------------------------------------------
// Chunked selective scan (n=2). NCH chunks of CHL steps.
// ---------------------------------------------------------------------------
__global__ __launch_bounds__(256) void scan_part1(
    const unsigned short* __restrict__ dt16,
    const unsigned short* __restrict__ xi16,
    const float* __restrict__ bc,
    const float* __restrict__ Alog,
    float4* __restrict__ hc)          // (B, NCH, DI)
{
    const int d  = blockIdx.x * 256 + threadIdx.x;
    const int b  = blockIdx.y;
    const int ch = blockIdx.z;
    const float A0 = -__expf(Alog[d * 2 + 0]);
    const float A1 = -__expf(Alog[d * 2 + 1]);
    float h0 = 0.f, h1 = 0.f, p0 = 1.f, p1 = 1.f;
    const int r0 = b * LSEQ + ch * CHL;
    #pragma unroll 4
    for (int l = 0; l < CHL; l++) {
        const int r = r0 + l;
        const float dtv = bf2f(dt16[(size_t)r * DI + d]);
        const float xiv = bf2f(xi16[(size_t)r * DI + d]);
        const float4 bcv = *(const float4*)(bc + r * 4);
        const float e0 = __expf(dtv * A0);
        const float e1 = __expf(dtv * A1);
        const float dbx = dtv * xiv;
        h0 = fmaf(e0, h0, dbx * bcv.x);
        h1 = fmaf(e1, h1, dbx * bcv.y);
        p0 *= e0; p1 *= e1;
    }
    hc[(size_t)(b * NCH + ch) * DI + d] = make_float4(h0, h1, p0, p1);
}

__global__ __launch_bounds__(256) void scan_carry(
    const float4* __restrict__ hc,
    float2* __restrict__ ci)          // (B, NCH, DI)
{
    const int d = blockIdx.x * 256 + threadIdx.x;
    const int b = blockIdx.y;
    float c0 = 0.f, c1 = 0.f;
    #pragma unroll
    for (int ch = 0; ch < NCH; ch++) {
        const size_t idx = (size_t)(b * NCH + ch) * DI + d;
        const float4 v = hc[idx];
        ci[idx] = make_float2(c0, c1);
        c0 = fmaf(v.z, c0, v.x);
        c1 = fmaf(v.w, c1, v.y);
    }
}

__global__ __launch_bounds__(256) void scan_part2(
    const unsigned short* __restrict__ dt16,
    const unsigned short* __restrict__ xi16,
    const unsigned short* __restrict__ xz16,  // z = cols [1024,2048)
    const float* __restrict__ bc,
    const float* __restrict__ Alog,
    const float* __restrict__ Dp,
    const float2* __restrict__ ci,
    unsigned short* __restrict__ yg16)
{
    const int d  = blockIdx.x * 256 + threadIdx.x;
    const int b  = blockIdx.y;
    const int ch = blockIdx.z;
    const float A0 = -__expf(Alog[d * 2 + 0]);
    const float A1 = -__expf(Alog[d * 2 + 1]);
    const float Dv = Dp[d];
    const float2 c = ci[(size_t)(b * NCH + ch) * DI + d];
    float h0 = c.x, h1 = c.y;
    const int r0 = b * LSEQ + ch * CHL;
    #pragma unroll 4
    for (int l = 0; l < CHL; l++) {
        const int r = r0 + l;
        const float dtv = bf2f(dt16[(size_t)r * DI + d]);
        const float xiv = bf2f(xi16[(size_t)r * DI + d]);
        const float4 bcv = *(const float4*)(bc + r * 4);
        const float zv = bf2f(xz16[(size_t)r * TWO_DI + DI + d]);
        const float e0 = __expf(dtv * A0);
        const float e1 = __expf(dtv * A1);
        const float dbx = dtv * xiv;
        h0 = fmaf(e0, h0, dbx * bcv.x);
        h1 = fmaf(e1, h1, dbx * bcv.y);
        const float y = fmaf(h0, bcv.z, fmaf(h1, bcv.w, Dv * xiv));
        yg16[(size_t)r * DI + d] = f2bf(y * siluf(zv));
    }
}

// ---------------------------------------------------------------------------
// LayerNorm over last dim (1024), in-place.
// ---------------------------------------------------------------------------
__global__ __launch_bounds__(256) void ln_kernel(
    float* __restrict__ s,
    const float* __restrict__ g,
    const float* __restrict__ bb)
{
    __shared__ float red[8];
    const size_t base = (size_t)blockIdx.x * DM;
    const int t = threadIdx.x;
    float x0 = s[base + t];
    float x1 = s[base + t + 256];
    float x2 = s[base + t + 512];
    float x3 = s[base + t + 768];
    float sum = x0 + x1 + x2 + x3;
    #pragma unroll
    for (int o = 32; o; o >>= 1) sum += __shfl_down(sum, o, 64);
    const int w = t >> 6, lane = t & 63;
    if (lane == 0) red[w] = sum;
    __syncthreads();
    const float m = (red[0] + red[1] + red[2] + red[3]) * (1.0f / 1024.0f);
    const float d0 = x0 - m, d1 = x1 - m, d2 = x2 - m, d3 = x3 - m;
    float ss = d0 * d0 + d1 * d1 + d2 * d2 + d3 * d3;
    #pragma unroll
    for (int o = 32; o; o >>= 1) ss += __shfl_down(ss, o, 64);
    if (lane == 0) red[4 + w] = ss;
    __syncthreads();
    const float var = (red[4] + red[5] + red[6] + red[7]) * (1.0f / 1024.0f);
    const float inv = rsqrtf(var + 1e-5f);
    s[base + t]       = d0 * inv * g[t]       + bb[t];
    s[base + t + 256] = d1 * inv * g[t + 256] + bb[t + 256];
    s[base + t + 512] = d2 * inv * g[t + 512] + bb[t + 512];
    s[base + t + 768] = d3 * inv * g[t + 768] + bb[t + 768];
}

// ---------------------------------------------------------------------------
// transpose + cast fp32 (b,256c,1024s) -> bf16 (b,1024s,256c)
// ---------------------------------------------------------------------------
__global__ __launch_bounds__(256) void transpose_cast(
    const float* __restrict__ in, unsigned short* __restrict__ out)
{
    __shared__ float tile[32][33];
    const int b = blockIdx.z;
    const int c0 = blockIdx.y * 32;
    const int s0 = blockIdx.x * 32;
    const int tx = threadIdx.x & 31;
    const int ty = threadIdx.x >> 5;   // 0..7
    const size_t ib = (size_t)b * 256 * 1024;
    const size_t ob = (size_t)b * 1024 * 256;
    #pragma unroll
    for (int i = 0; i < 4; i++)
        tile[tx][ty + i * 8] = in[ib + (size_t)(c0 + ty + i * 8) * 1024 + s0 + tx];
    __syncthreads();
    #pragma unroll
    for (int i = 0; i < 4; i++)
        out[ob + (size_t)(s0 + ty + i * 8) * 256 + c0 + tx] = f2bf(tile[ty + i * 8][tx]);
}

// bf16 in -> bf16 out transpose
__global__ __launch_bounds__(256) void transpose16(
    const unsigned short* __restrict__ in, unsigned short* __restrict__ out)
{
    __shared__ unsigned short tile[32][34];
    const int b = blockIdx.z;
    const int c0 = blockIdx.y * 32;
    const int s0 = blockIdx.x * 32;
    const int tx = threadIdx.x & 31;
    const int ty = threadIdx.x >> 5;
    const size_t ib = (size_t)b * 256 * 1024;
    const size_t ob = (size_t)b * 1024 * 256;
    #pragma unroll
    for (int i = 0; i < 4; i++)
        tile[tx][ty + i * 8] = in[ib + (size_t)(c0 + ty + i * 8) * 1024 + s0 + tx];
    __syncthreads();
    #pragma unroll
    for (int i = 0; i < 4; i++)
        out[ob + (size_t)(s0 + ty + i * 8) * 256 + c0 + tx] = tile[ty + i * 8][tx];
}

// ---------------------------------------------------------------------------
extern "C" void kernel_launch(void* const* d_in, const int* in_sizes, int n_in,
                              void* d_out, int out_size, void* d_ws, size_t ws_size,
                              hipStream_t stream)
{
    const float* x        = (const float*)d_in[0];
    const float* m1_Win   = (const float*)d_in[1];
    const float* m1_convw = (const float*)d_in[2];
    const float* m1_convb = (const float*)d_in[3];
    const float* m1_Wx    = (const float*)d_in[4];
    const float* m1_Wdt   = (const float*)d_in[5];
    const float* m1_bdt   = (const float*)d_in[6];
    const float* m1_Alog  = (const float*)d_in[7];
    const float* m1_D     = (const float*)d_in[8];
    const float* m1_Wout  = (const float*)d_in[9];
    const float* m2_Win   = (const float*)d_in[10];
    const float* m2_convw = (const float*)d_in[11];
    const float* m2_convb = (const float*)d_in[12];
    const float* m2_Wx    = (const float*)d_in[13];
    const float* m2_Wdt   = (const float*)d_in[14];
    const float* m2_bdt   = (const float*)d_in[15];
    const float* m2_Alog  = (const float*)d_in[16];
    const float* m2_D     = (const float*)d_in[17];
    const float* m2_Wout  = (const float*)d_in[18];
    const float* ln1_g    = (const float*)d_in[19];
    const float* ln1_b    = (const float*)d_in[20];
    const float* ln2_g    = (const float*)d_in[21];
    const float* ln2_b    = (const float*)d_in[22];
    const float* W_mid    = (const float*)d_in[23];
    const float* W_spa    = (const float*)d_in[24];
    const float* b_spa    = (const float*)d_in[25];
    const float* W_res    = (const float*)d_in[26];

    float* ws = (float*)d_ws;
    size_t off = 0;
    float* buf_s   = ws + off; off += (size_t)NROWS * DI;              // 16 MB
    float* buf_bc  = ws + off; off += (size_t)NROWS * 4;
    float4* buf_hc = (float4*)(ws + off); off += (size_t)BATCH * NCH * DI * 4;
    float2* buf_ci = (float2*)(ws + off); off += (size_t)BATCH * NCH * DI * 2;
    unsigned short* xz16   = (unsigned short*)(ws + off); off += (size_t)NROWS * TWO_DI / 2; // 16 MB
    unsigned short* bx     = (unsigned short*)(ws + off); off += (size_t)NROWS * DI / 2;
    unsigned short* xi16   = (unsigned short*)(ws + off); off += (size_t)NROWS * DI / 2;
    unsigned short* yg16   = (unsigned short*)(ws + off); off += (size_t)NROWS * DI / 2;
    unsigned short* sT16   = (unsigned short*)(ws + off); off += (size_t)NROWS * DI / 2;
    unsigned short* dt16   = (unsigned short*)(ws + off); off += (size_t)NROWS * DI / 2;
    unsigned short* res16  = (unsigned short*)(ws + off); off += (size_t)NROWS * DI / 2;
    unsigned short* win1   = (unsigned short*)(ws + off); off += (size_t)TWO_DI * DM / 2;
    unsigned short* wout1  = (unsigned short*)(ws + off); off += (size_t)DM * DI / 2;
    unsigned short* win2   = (unsigned short*)(ws + off); off += (size_t)TWO_DI * DM / 2;
    unsigned short* wout2  = (unsigned short*)(ws + off); off += (size_t)DM * DI / 2;
    unsigned short* wspa16 = (unsigned short*)(ws + off); off += (size_t)DM * DM / 2;
    unsigned short* wcomb1 = (unsigned short*)(ws + off); off += (size_t)DI * DI / 2;
    unsigned short* wcomb2 = (unsigned short*)(ws + off); off += (size_t)DI * DI / 2;
    unsigned short* wmid16 = (unsigned short*)(ws + off); off += (size_t)LSEQ * LSEQ / 2;
    unsigned short* wres16 = (unsigned short*)(ws + off); off += (size_t)LSEQ * LSEQ / 2;
    unsigned short* t16  = yg16;   // mix1 out / mamba2 in (lifetimes disjoint)
    unsigned short* rT16 = sT16;   // residual transpose after mix1 consumed sT16
    (void)ws_size; (void)n_in; (void)in_sizes; (void)out_size;

    const dim3 blk(256);

    // ---- all input casts in one dispatch ----
    cast8<<<dim3(11392), blk, 0, stream>>>(
        x, bx, m1_Win, win1, m1_Wout, wout1, m2_Win, win2, m2_Wout, wout2,
        W_spa, wspa16, W_mid, wmid16, W_res, wres16);
    // ---- both Wcomb = Wdt @ Wx[:64] ----
    gemm_nn_wcomb<<<dim3(16, 16, 2), blk, 0, stream>>>(
        m1_Wdt, m1_Wx, wcomb1, m2_Wdt, m2_Wx, wcomb2);

    auto mamba = [&](const unsigned short* inp16, const unsigned short* win16,
                     const unsigned short* wcomb16, const unsigned short* wout16,
                     const float* convw, const float* convb, const float* Wx,
                     const float* bdt, const float* Alog, const float* Dp,
                     float* out_buf) {
        // xz16 = bf16(inp @ Win.T) : (4096,2048)  [2048 blocks x 4 waves]
        gemm_sk<0, 1, 0, 0><<<dim3(TWO_DI / 64, NROWS / 64), blk, 0, stream>>>(
            (const short*)inp16, (const short*)win16, nullptr, nullptr,
            (void*)xz16, NROWS, TWO_DI, DM);
        // conv + silu + fused B/C projection -> xi16, bc
        conv_silu_bc<<<dim3(NROWS), blk, 0, stream>>>(
            xz16, convw, convb, Wx, xi16, buf_bc);
        // dt16 = bf16(softplus(xi @ Wcomb.T + bdt))  [1024 blocks x 4 waves]
        gemm_sk<1, 1, 0, 0><<<dim3(DI / 64, NROWS / 64), blk, 0, stream>>>(
            (const short*)xi16, (const short*)wcomb16, bdt, nullptr,
            (void*)dt16, NROWS, DI, DI);
        // chunked scan -> yg16
        scan_part1<<<dim3(DI / 256, BATCH, NCH), blk, 0, stream>>>(
            dt16, xi16, buf_bc, Alog, buf_hc);
        scan_carry<<<dim3(DI / 256, BATCH), blk, 0, stream>>>(buf_hc, buf_ci);
        scan_part2<<<dim3(DI / 256, BATCH, NCH), blk, 0, stream>>>(
            dt16, xi16, xz16, buf_bc, Alog, Dp, buf_ci, yg16);
        // out = yg @ Wout.T : (4096,1024) fp32  [1024 blocks x 4 waves]
        gemm_sk<0, 0, 0, 0><<<dim3(DM / 64, NROWS / 64), blk, 0, stream>>>(
            (const short*)yg16, (const short*)wout16, nullptr, nullptr,
            (void*)out_buf, NROWS, DM, DI);
    };

    // ---- Mamba 1 + LN1 ----
    mamba(bx, win1, wcomb1, wout1, m1_convw, m1_convb, m1_Wx, m1_bdt,
          m1_Alog, m1_D, buf_s);
    ln_kernel<<<dim3(NROWS), blk, 0, stream>>>(buf_s, ln1_g, ln1_b);

    // ---- channel mix 1: t16[b] = bf16(silu(W_mid @ s[b])) ----
    transpose_cast<<<dim3(32, 8, BATCH), blk, 0, stream>>>(buf_s, sT16);
    gemm_sk<3, 1, 1, 0><<<dim3(DM / 64, LSEQ / 64, BATCH), blk, 0, stream>>>(
        (const short*)wmid16, (const short*)sT16, nullptr, nullptr,
        (void*)t16, LSEQ, DM, LSEQ);

    // ---- Mamba 2 + LN2 ----
    mamba(t16, win2, wcomb2, wout2, m2_convw, m2_convb, m2_Wx, m2_bdt,
          m2_Alog, m2_D, buf_s);
    ln_kernel<<<dim3(NROWS), blk, 0, stream>>>(buf_s, ln2_g, ln2_b);

    // ---- residual path: res16 = bf16(silu(x @ W_spa.T + b_spa)) ----
    gemm_sk<2, 1, 0, 0><<<dim3(DM / 64, NROWS / 64), blk, 0, stream>>>(
        (const short*)bx, (const short*)wspa16, b_spa, nullptr,
        (void*)res16, NROWS, DM, DM);
    transpose16<<<dim3(32, 8, BATCH), blk, 0, stream>>>(res16, rT16);
    // mix2 + final fuse: d_out = silu(s + silu(W_res @ r))
    gemm_sk<3, 0, 1, 1><<<dim3(DM / 64, LSEQ / 64, BATCH), blk, 0, stream>>>(
        (const short*)wres16, (const short*)rT16, nullptr, buf_s,
        d_out, LSEQ, DM, LSEQ);
}

// Round 9
// 457.019 us; speedup vs baseline: 1.0339x; 1.0139x over previous
//
#include <hip/hip_runtime.h>
#include <math.h>

// Problem constants (B=16, L=C=256 scan axis, dm=di=1024, n=2, dtr=64, k=4)
#define BATCH 16
#define LSEQ  256
#define DM    1024
#define DI    1024
#define NROWS (BATCH*LSEQ)   // 4096
#define DTR   64
#define TWO_DI 2048
#define NCH   16             // scan chunks
#define CHL   16             // chunk length (NCH*CHL == LSEQ)

typedef __attribute__((ext_vector_type(8))) short short8;
typedef __attribute__((ext_vector_type(4))) float floatx4;
typedef __attribute__((ext_vector_type(4))) unsigned short ushortx4;

__device__ __forceinline__ float siluf(float x) {
    return x / (1.0f + __expf(-x));
}
__device__ __forceinline__ float softplusf(float x) {
    return fmaxf(x, 0.0f) + log1pf(__expf(-fabsf(x)));
}
// fp32 -> bf16 (RNE), raw bits
__device__ __forceinline__ unsigned short f2bf(float f) {
    unsigned int u = __float_as_uint(f);
    u += 0x7fffu + ((u >> 16) & 1u);
    return (unsigned short)(u >> 16);
}
__device__ __forceinline__ float bf2f(unsigned short s) {
    return __uint_as_float(((unsigned int)s) << 16);
}
// async global->LDS, 16B per lane; LDS dest = wave-uniform base + lane*16
__device__ __forceinline__ void async16(const short* g, short* l) {
    __builtin_amdgcn_global_load_lds(
        (const __attribute__((address_space(1))) unsigned int*)g,
        (__attribute__((address_space(3))) unsigned int*)l,
        16, 0, 0);
}
// per-wave wait for ALL outstanding vmem (incl. global_load_lds) -- no barrier.
// simm16: vmcnt=0, expcnt=7 (ignore), lgkmcnt=15 (ignore) -> 0x0F70.
__device__ __forceinline__ void wait_vm0() {
    __builtin_amdgcn_s_waitcnt(0x0F70);
}

// ---------------------------------------------------------------------------
// cast8: all fp32->bf16 input casts in ONE dispatch. 1024 elts per block.
// ---------------------------------------------------------------------------
__global__ __launch_bounds__(256) void cast8(
    const float* __restrict__ x,    unsigned short* __restrict__ ox,
    const float* __restrict__ w1i,  unsigned short* __restrict__ o1i,
    const float* __restrict__ w1o,  unsigned short* __restrict__ o1o,
    const float* __restrict__ w2i,  unsigned short* __restrict__ o2i,
    const float* __restrict__ w2o,  unsigned short* __restrict__ o2o,
    const float* __restrict__ wsp,  unsigned short* __restrict__ osp,
    const float* __restrict__ wmd,  unsigned short* __restrict__ omd,
    const float* __restrict__ wrs,  unsigned short* __restrict__ ors)
{
    const int b = blockIdx.x;
    const float* in; unsigned short* out; int base;
    if      (b <  4096) { in = x;   out = ox;  base = 0; }
    else if (b <  6144) { in = w1i; out = o1i; base = 4096; }
    else if (b <  7168) { in = w1o; out = o1o; base = 6144; }
    else if (b <  9216) { in = w2i; out = o2i; base = 7168; }
    else if (b < 10240) { in = w2o; out = o2o; base = 9216; }
    else if (b < 11264) { in = wsp; out = osp; base = 10240; }
    else if (b < 11328) { in = wmd; out = omd; base = 11264; }
    else                { in = wrs; out = ors; base = 11328; }
    const size_t i = ((size_t)(b - base) * 256 + threadIdx.x) * 4;
    const float4 v = *(const float4*)(in + i);
    union { unsigned short s[4]; unsigned long long u; } p;
    p.s[0] = f2bf(v.x); p.s[1] = f2bf(v.y);
    p.s[2] = f2bf(v.z); p.s[3] = f2bf(v.w);
    *(unsigned long long*)(out + i) = p.u;
}

// ---------------------------------------------------------------------------
// Split-K bf16 MFMA GEMM (nt): C[M,N] = A[M,K] @ W[N,K]^T.
// 256 thr = 4 waves; 64x64 tile; each wave does a K/4 slice with private
// 8 KB LDS staging, per-wave vmcnt(0), NO barrier in K-loop; cross-wave
// LDS reduction at the end.
// SWZ: XCD-aware block remap (round-robin lin%8 -> XCD) so each XCD's
// A-slice + W-slice fit its 4 MB L2 (R8 showed we are L3-BW-bound at
// 5.4 TB/s; local L2 aggregate is ~34.5 TB/s):
//   SWZ=1: grid (16,64)  -> XCD x: row-tiles [8x,8x+8) x 16 cols (A 1MB+W 2MB)
//   SWZ=2: grid (32,64)  -> 4 row-grp x 2 col-grp of 16x16     (A 2MB+W 2MB)
// EP: 0=none, 1=softplus(v+bias[c]), 2=silu(v+bias[c]), 3=silu(v)
// OUT16: bf16 out. BATW: W,C batched by blockIdx.z. FIN: v=silu(Sadd+v').
// Requires M%64==0, N%64==0, (K/4)%32==0.
// ---------------------------------------------------------------------------
template <int EP, int OUT16, int BATW, int FIN, int SWZ>
__global__ __launch_bounds__(256) void gemm_sk(
    const short* __restrict__ A,
    const short* __restrict__ W,
    const float* __restrict__ bias,
    const float* __restrict__ Sadd,
    void* __restrict__ Cout,
    int M, int N, int K)
{
    __shared__ float fl[8192];   // 32 KB: staging (4 x 8 KB) then reduction

    const int bz = BATW ? blockIdx.z : 0;
    const short* Wb = W + (size_t)bz * N * K;
    const size_t cbase = (size_t)bz * M * N;

    int bx = blockIdx.x, by = blockIdx.y;
    if (SWZ == 1) {              // grid (16,64): 1024 blocks
        const int lin = blockIdx.x + (blockIdx.y << 4);
        const int xcd = lin & 7;
        const int s   = lin >> 3;            // [0,128)
        by = xcd * 8 + (s & 7);              // row-tile [0,64)
        bx = s >> 3;                         // col-tile [0,16)
    } else if (SWZ == 2) {       // grid (32,64): 2048 blocks
        const int lin = blockIdx.x + (blockIdx.y << 5);
        const int xcd = lin & 7;
        const int s   = lin >> 3;            // [0,256)
        by = (xcd & 3) * 16 + (s & 15);      // row-tile [0,64)
        bx = (xcd >> 2) * 16 + (s >> 4);     // col-tile [0,32)
    }

    const int tid  = threadIdx.x;
    const int w    = tid >> 6;
    const int lane = tid & 63;
    const int row0 = by * 64;
    const int col0 = bx * 64;

    const int Kw  = K >> 2;        // per-wave K slice
    const int wk0 = w * Kw;

    const int srow  = lane >> 2;         // 0..15
    const int skoff = (lane & 3) * 8;    // k elts
    const short* gA = A  + (size_t)(row0 + srow) * K + wk0 + skoff;
    const short* gB = Wb + (size_t)(col0 + srow) * K + wk0 + skoff;
    short* st = (short*)fl + w * 4096;   // this wave's 8 KB staging region
    short* lA = st + lane * 8;           // A at +0 (64x32), B at +2048
    short* lB = lA + 2048;

    const int fr = lane & 15;
    const int fk = (lane >> 4) * 8;
    const int q  = lane >> 4;

    floatx4 acc[4][4] = {};

    for (int kk = 0; kk < Kw; kk += 32) {
        #pragma unroll
        for (int r = 0; r < 4; r++) {
            async16(gA + (size_t)(r * 16) * K + kk, lA + r * 512);
            async16(gB + (size_t)(r * 16) * K + kk, lB + r * 512);
        }
        wait_vm0();   // per-wave: DMA-to-LDS complete before ds_read (NO barrier)
        short8 af[4], bf[4];
        #pragma unroll
        for (int t = 0; t < 4; t++) {
            af[t] = *(const short8*)&st[(t * 16 + fr) * 32 + fk];
            bf[t] = *(const short8*)&st[2048 + (t * 16 + fr) * 32 + fk];
        }
        #pragma unroll
        for (int i = 0; i < 4; i++)
            #pragma unroll
            for (int j = 0; j < 4; j++)
                acc[i][j] = __builtin_amdgcn_mfma_f32_16x16x32_bf16(
                    af[i], bf[j], acc[i][j], 0, 0, 0);
    }

    // two-phase cross-wave reduction (rows [0,32) then [32,64))
    #pragma unroll
    for (int p = 0; p < 2; p++) {
        __syncthreads();   // phase 0: all K-loops done; phase 1: reduce reads done
        #pragma unroll
        for (int i = 0; i < 2; i++) {        // global acc i = 2p + i
            #pragma unroll
            for (int j = 0; j < 4; j++) {
                #pragma unroll
                for (int r = 0; r < 4; r++) {
                    const int rloc = i * 16 + q * 4 + r;   // 0..31
                    const int col  = j * 16 + fr;
                    fl[w * 2048 + rloc * 64 + col] = acc[2 * p + i][j][r];
                }
            }
        }
        __syncthreads();
        #pragma unroll
        for (int v = 0; v < 2; v++) {
            const int f = tid * 2 + v;       // 0..511 float4s of 32x64 tile
            const int rloc = f >> 4;
            const int cb = (f & 15) * 4;
            const float* p0 = &fl[rloc * 64 + cb];
            const float4 s0 = *(const float4*)(p0);
            const float4 s1 = *(const float4*)(p0 + 2048);
            const float4 s2 = *(const float4*)(p0 + 4096);
            const float4 s3 = *(const float4*)(p0 + 6144);
            float sv[4] = { s0.x + s1.x + s2.x + s3.x,
                            s0.y + s1.y + s2.y + s3.y,
                            s0.z + s1.z + s2.z + s3.z,
                            s0.w + s1.w + s2.w + s3.w };
            const int grow = row0 + p * 32 + rloc;
            #pragma unroll
            for (int e = 0; e < 4; e++) {
                const int c = col0 + cb + e;
                float vv = sv[e];
                if (EP == 1) vv = softplusf(vv + bias[c]);
                else if (EP == 2) vv = siluf(vv + bias[c]);
                else if (EP == 3) vv = siluf(vv);
                const size_t idx = cbase + (size_t)grow * N + c;
                if (FIN) vv = siluf(Sadd[idx] + vv);
                if (OUT16) ((unsigned short*)Cout)[idx] = f2bf(vv);
                else       ((float*)Cout)[idx] = vv;
            }
        }
    }
}

// ---------------------------------------------------------------------------
// Both Wcomb = Wdt(1024x64) @ Wx[:64](64x1024) in one dispatch (z = layer).
// ---------------------------------------------------------------------------
__global__ __launch_bounds__(256) void gemm_nn_wcomb(
    const float* __restrict__ Wdt1, const float* __restrict__ Wx1,
    unsigned short* __restrict__ C1,
    const float* __restrict__ Wdt2, const float* __restrict__ Wx2,
    unsigned short* __restrict__ C2)
{
    const float* Wdt = blockIdx.z ? Wdt2 : Wdt1;
    const float* Wx  = blockIdx.z ? Wx2  : Wx1;
    unsigned short* C16 = blockIdx.z ? C2 : C1;

    __shared__ float Asf[16][64];
    __shared__ float Bsf[16][64];

    const int tid = threadIdx.x;
    const int tx = tid & 15;
    const int ty = tid >> 4;
    const int row0 = blockIdx.y * 64;
    const int col0 = blockIdx.x * 64;
    const int lrow = tid >> 2;
    const int lcol = (tid & 3) * 4;
    const int bk = tid >> 4;
    const int bn = (tid & 15) * 4;

    float acc[4][4] = {};

    for (int k0 = 0; k0 < 64; k0 += 16) {
        const float4 av = *(const float4*)(Wdt + (size_t)(row0 + lrow) * 64 + k0 + lcol);
        Asf[lcol + 0][lrow] = av.x;
        Asf[lcol + 1][lrow] = av.y;
        Asf[lcol + 2][lrow] = av.z;
        Asf[lcol + 3][lrow] = av.w;
        *(float4*)&Bsf[bk][bn] = *(const float4*)(Wx + (size_t)(k0 + bk) * 1024 + col0 + bn);
        __syncthreads();

        #pragma unroll
        for (int kk = 0; kk < 16; kk++) {
            const float4 a = *(const float4*)&Asf[kk][ty * 4];
            const float4 b = *(const float4*)&Bsf[kk][tx * 4];
            const float af[4] = {a.x, a.y, a.z, a.w};
            const float bfv[4] = {b.x, b.y, b.z, b.w};
            #pragma unroll
            for (int i = 0; i < 4; i++)
                #pragma unroll
                for (int j = 0; j < 4; j++)
                    acc[i][j] = fmaf(af[i], bfv[j], acc[i][j]);
        }
        __syncthreads();
    }

    #pragma unroll
    for (int i = 0; i < 4; i++) {
        const int r = row0 + ty * 4 + i;
        #pragma unroll
        for (int j = 0; j < 4; j++)
            C16[(size_t)r * 1024 + col0 + tx * 4 + j] = f2bf(acc[i][j]);
    }
}

// ---------------------------------------------------------------------------
// Depthwise causal conv (k=4) + bias + SiLU, fused B/C projection.
// ---------------------------------------------------------------------------
__global__ __launch_bounds__(256) void conv_silu_bc(
    const unsigned short* __restrict__ xz16,
    const float* __restrict__ convw,
    const float* __restrict__ convb,
    const float* __restrict__ Wx,     // (68, 1024): rows 64..67 = B0,B1,C0,C1
    unsigned short* __restrict__ xi16,
    float* __restrict__ bc)           // (4096, 4)
{
    __shared__ float redc[4][4];
    const int r = blockIdx.x;
    const int l = r & (LSEQ - 1);
    const int tid = threadIdx.x;
    const int d0 = tid * 4;

    ushortx4 x0 = *(const ushortx4*)(xz16 + (size_t)r * TWO_DI + d0);
    ushortx4 x1 = {0,0,0,0}, x2 = {0,0,0,0}, x3 = {0,0,0,0};
    if (l >= 1) x1 = *(const ushortx4*)(xz16 + (size_t)(r - 1) * TWO_DI + d0);
    if (l >= 2) x2 = *(const ushortx4*)(xz16 + (size_t)(r - 2) * TWO_DI + d0);
    if (l >= 3) x3 = *(const ushortx4*)(xz16 + (size_t)(r - 3) * TWO_DI + d0);

    float p0 = 0.f, p1 = 0.f, p2 = 0.f, p3 = 0.f;
    ushortx4 outv;
    #pragma unroll
    for (int j = 0; j < 4; j++) {
        const int d = d0 + j;
        const float4 w = *(const float4*)(convw + d * 4);
        float acc = w.w * bf2f(x0[j]);
        acc = fmaf(w.z, bf2f(x1[j]), acc);
        acc = fmaf(w.y, bf2f(x2[j]), acc);
        acc = fmaf(w.x, bf2f(x3[j]), acc);
        const float v = siluf(acc + convb[d]);
        outv[j] = f2bf(v);
        p0 = fmaf(v, Wx[64 * 1024 + d], p0);
        p1 = fmaf(v, Wx[65 * 1024 + d], p1);
        p2 = fmaf(v, Wx[66 * 1024 + d], p2);
        p3 = fmaf(v, Wx[67 * 1024 + d], p3);
    }
    *(ushortx4*)(xi16 + (size_t)r * DI + d0) = outv;

    #pragma unroll
    for (int o = 32; o; o >>= 1) {
        p0 += __shfl_down(p0, o, 64);
        p1 += __shfl_down(p1, o, 64);
        p2 += __shfl_down(p2, o, 64);
        p3 += __shfl_down(p3, o, 64);
    }
    const int w = tid >> 6, lane = tid & 63;
    if (lane == 0) {
        redc[w][0] = p0; redc[w][1] = p1; redc[w][2] = p2; redc[w][3] = p3;
    }
    __syncthreads();
    if (tid < 4)
        bc[r * 4 + tid] = redc[0][tid] + redc[1][tid] + redc[2][tid] + redc[3][tid];
}

// ---------------------------------------------------------------------------
// Chunked selective scan (n=2). NCH chunks of CHL steps.
// ---------------------------------------------------------------------------
__global__ __launch_bounds__(256) void scan_part1(
    const unsigned short* __restrict__ dt16,
    const unsigned short* __restrict__ xi16,
    const float* __restrict__ bc,
    const float* __restrict__ Alog,
    float4* __restrict__ hc)          // (B, NCH, DI)
{
    const int d  = blockIdx.x * 256 + threadIdx.x;
    const int b  = blockIdx.y;
    const int ch = blockIdx.z;
    const float A0 = -__expf(Alog[d * 2 + 0]);
    const float A1 = -__expf(Alog[d * 2 + 1]);
    float h0 = 0.f, h1 = 0.f, p0 = 1.f, p1 = 1.f;
    const int r0 = b * LSEQ + ch * CHL;
    #pragma unroll 4
    for (int l = 0; l < CHL; l++) {
        const int r = r0 + l;
        const float dtv = bf2f(dt16[(size_t)r * DI + d]);
        const float xiv = bf2f(xi16[(size_t)r * DI + d]);
        const float4 bcv = *(const float4*)(bc + r * 4);
        const float e0 = __expf(dtv * A0);
        const float e1 = __expf(dtv * A1);
        const float dbx = dtv * xiv;
        h0 = fmaf(e0, h0, dbx * bcv.x);
        h1 = fmaf(e1, h1, dbx * bcv.y);
        p0 *= e0; p1 *= e1;
    }
    hc[(size_t)(b * NCH + ch) * DI + d] = make_float4(h0, h1, p0, p1);
}

__global__ __launch_bounds__(256) void scan_carry(
    const float4* __restrict__ hc,
    float2* __restrict__ ci)          // (B, NCH, DI)
{
    const int d = blockIdx.x * 256 + threadIdx.x;
    const int b = blockIdx.y;
    float c0 = 0.f, c1 = 0.f;
    #pragma unroll
    for (int ch = 0; ch < NCH; ch++) {
        const size_t idx = (size_t)(b * NCH + ch) * DI + d;
        const float4 v = hc[idx];
        ci[idx] = make_float2(c0, c1);
        c0 = fmaf(v.z, c0, v.x);
        c1 = fmaf(v.w, c1, v.y);
    }
}

__global__ __launch_bounds__(256) void scan_part2(
    const unsigned short* __restrict__ dt16,
    const unsigned short* __restrict__ xi16,
    const unsigned short* __restrict__ xz16,  // z = cols [1024,2048)
    const float* __restrict__ bc,
    const float* __restrict__ Alog,
    const float* __restrict__ Dp,
    const float2* __restrict__ ci,
    unsigned short* __restrict__ yg16)
{
    const int d  = blockIdx.x * 256 + threadIdx.x;
    const int b  = blockIdx.y;
    const int ch = blockIdx.z;
    const float A0 = -__expf(Alog[d * 2 + 0]);
    const float A1 = -__expf(Alog[d * 2 + 1]);
    const float Dv = Dp[d];
    const float2 c = ci[(size_t)(b * NCH + ch) * DI + d];
    float h0 = c.x, h1 = c.y;
    const int r0 = b * LSEQ + ch * CHL;
    #pragma unroll 4
    for (int l = 0; l < CHL; l++) {
        const int r = r0 + l;
        const float dtv = bf2f(dt16[(size_t)r * DI + d]);
        const float xiv = bf2f(xi16[(size_t)r * DI + d]);
        const float4 bcv = *(const float4*)(bc + r * 4);
        const float zv = bf2f(xz16[(size_t)r * TWO_DI + DI + d]);
        const float e0 = __expf(dtv * A0);
        const float e1 = __expf(dtv * A1);
        const float dbx = dtv * xiv;
        h0 = fmaf(e0, h0, dbx * bcv.x);
        h1 = fmaf(e1, h1, dbx * bcv.y);
        const float y = fmaf(h0, bcv.z, fmaf(h1, bcv.w, Dv * xiv));
        yg16[(size_t)r * DI + d] = f2bf(y * siluf(zv));
    }
}

// ---------------------------------------------------------------------------
// LayerNorm over last dim (1024), in-place.
// ---------------------------------------------------------------------------
__global__ __launch_bounds__(256) void ln_kernel(
    float* __restrict__ s,
    const float* __restrict__ g,
    const float* __restrict__ bb)
{
    __shared__ float red[8];
    const size_t base = (size_t)blockIdx.x * DM;
    const int t = threadIdx.x;
    float x0 = s[base + t];
    float x1 = s[base + t + 256];
    float x2 = s[base + t + 512];
    float x3 = s[base + t + 768];
    float sum = x0 + x1 + x2 + x3;
    #pragma unroll
    for (int o = 32; o; o >>= 1) sum += __shfl_down(sum, o, 64);
    const int w = t >> 6, lane = t & 63;
    if (lane == 0) red[w] = sum;
    __syncthreads();
    const float m = (red[0] + red[1] + red[2] + red[3]) * (1.0f / 1024.0f);
    const float d0 = x0 - m, d1 = x1 - m, d2 = x2 - m, d3 = x3 - m;
    float ss = d0 * d0 + d1 * d1 + d2 * d2 + d3 * d3;
    #pragma unroll
    for (int o = 32; o; o >>= 1) ss += __shfl_down(ss, o, 64);
    if (lane == 0) red[4 + w] = ss;
    __syncthreads();
    const float var = (red[4] + red[5] + red[6] + red[7]) * (1.0f / 1024.0f);
    const float inv = rsqrtf(var + 1e-5f);
    s[base + t]       = d0 * inv * g[t]       + bb[t];
    s[base + t + 256] = d1 * inv * g[t + 256] + bb[t + 256];
    s[base + t + 512] = d2 * inv * g[t + 512] + bb[t + 512];
    s[base + t + 768] = d3 * inv * g[t + 768] + bb[t + 768];
}

// ---------------------------------------------------------------------------
// transpose + cast fp32 (b,256c,1024s) -> bf16 (b,1024s,256c)
// ---------------------------------------------------------------------------
__global__ __launch_bounds__(256) void transpose_cast(
    const float* __restrict__ in, unsigned short* __restrict__ out)
{
    __shared__ float tile[32][33];
    const int b = blockIdx.z;
    const int c0 = blockIdx.y * 32;
    const int s0 = blockIdx.x * 32;
    const int tx = threadIdx.x & 31;
    const int ty = threadIdx.x >> 5;   // 0..7
    const size_t ib = (size_t)b * 256 * 1024;
    const size_t ob = (size_t)b * 1024 * 256;
    #pragma unroll
    for (int i = 0; i < 4; i++)
        tile[tx][ty + i * 8] = in[ib + (size_t)(c0 + ty + i * 8) * 1024 + s0 + tx];
    __syncthreads();
    #pragma unroll
    for (int i = 0; i < 4; i++)
        out[ob + (size_t)(s0 + ty + i * 8) * 256 + c0 + tx] = f2bf(tile[ty + i * 8][tx]);
}

// bf16 in -> bf16 out transpose
__global__ __launch_bounds__(256) void transpose16(
    const unsigned short* __restrict__ in, unsigned short* __restrict__ out)
{
    __shared__ unsigned short tile[32][34];
    const int b = blockIdx.z;
    const int c0 = blockIdx.y * 32;
    const int s0 = blockIdx.x * 32;
    const int tx = threadIdx.x & 31;
    const int ty = threadIdx.x >> 5;
    const size_t ib = (size_t)b * 256 * 1024;
    const size_t ob = (size_t)b * 1024 * 256;
    #pragma unroll
    for (int i = 0; i < 4; i++)
        tile[tx][ty + i * 8] = in[ib + (size_t)(c0 + ty + i * 8) * 1024 + s0 + tx];
    __syncthreads();
    #pragma unroll
    for (int i = 0; i < 4; i++)
        out[ob + (size_t)(s0 + ty + i * 8) * 256 + c0 + tx] = tile[ty + i * 8][tx];
}

// ---------------------------------------------------------------------------
extern "C" void kernel_launch(void* const* d_in, const int* in_sizes, int n_in,
                              void* d_out, int out_size, void* d_ws, size_t ws_size,
                              hipStream_t stream)
{
    const float* x        = (const float*)d_in[0];
    const float* m1_Win   = (const float*)d_in[1];
    const float* m1_convw = (const float*)d_in[2];
    const float* m1_convb = (const float*)d_in[3];
    const float* m1_Wx    = (const float*)d_in[4];
    const float* m1_Wdt   = (const float*)d_in[5];
    const float* m1_bdt   = (const float*)d_in[6];
    const float* m1_Alog  = (const float*)d_in[7];
    const float* m1_D     = (const float*)d_in[8];
    const float* m1_Wout  = (const float*)d_in[9];
    const float* m2_Win   = (const float*)d_in[10];
    const float* m2_convw = (const float*)d_in[11];
    const float* m2_convb = (const float*)d_in[12];
    const float* m2_Wx    = (const float*)d_in[13];
    const float* m2_Wdt   = (const float*)d_in[14];
    const float* m2_bdt   = (const float*)d_in[15];
    const float* m2_Alog  = (const float*)d_in[16];
    const float* m2_D     = (const float*)d_in[17];
    const float* m2_Wout  = (const float*)d_in[18];
    const float* ln1_g    = (const float*)d_in[19];
    const float* ln1_b    = (const float*)d_in[20];
    const float* ln2_g    = (const float*)d_in[21];
    const float* ln2_b    = (const float*)d_in[22];
    const float* W_mid    = (const float*)d_in[23];
    const float* W_spa    = (const float*)d_in[24];
    const float* b_spa    = (const float*)d_in[25];
    const float* W_res    = (const float*)d_in[26];

    float* ws = (float*)d_ws;
    size_t off = 0;
    float* buf_s   = ws + off; off += (size_t)NROWS * DI;              // 16 MB
    float* buf_bc  = ws + off; off += (size_t)NROWS * 4;
    float4* buf_hc = (float4*)(ws + off); off += (size_t)BATCH * NCH * DI * 4;
    float2* buf_ci = (float2*)(ws + off); off += (size_t)BATCH * NCH * DI * 2;
    unsigned short* xz16   = (unsigned short*)(ws + off); off += (size_t)NROWS * TWO_DI / 2; // 16 MB
    unsigned short* bx     = (unsigned short*)(ws + off); off += (size_t)NROWS * DI / 2;
    unsigned short* xi16   = (unsigned short*)(ws + off); off += (size_t)NROWS * DI / 2;
    unsigned short* yg16   = (unsigned short*)(ws + off); off += (size_t)NROWS * DI / 2;
    unsigned short* sT16   = (unsigned short*)(ws + off); off += (size_t)NROWS * DI / 2;
    unsigned short* dt16   = (unsigned short*)(ws + off); off += (size_t)NROWS * DI / 2;
    unsigned short* res16  = (unsigned short*)(ws + off); off += (size_t)NROWS * DI / 2;
    unsigned short* win1   = (unsigned short*)(ws + off); off += (size_t)TWO_DI * DM / 2;
    unsigned short* wout1  = (unsigned short*)(ws + off); off += (size_t)DM * DI / 2;
    unsigned short* win2   = (unsigned short*)(ws + off); off += (size_t)TWO_DI * DM / 2;
    unsigned short* wout2  = (unsigned short*)(ws + off); off += (size_t)DM * DI / 2;
    unsigned short* wspa16 = (unsigned short*)(ws + off); off += (size_t)DM * DM / 2;
    unsigned short* wcomb1 = (unsigned short*)(ws + off); off += (size_t)DI * DI / 2;
    unsigned short* wcomb2 = (unsigned short*)(ws + off); off += (size_t)DI * DI / 2;
    unsigned short* wmid16 = (unsigned short*)(ws + off); off += (size_t)LSEQ * LSEQ / 2;
    unsigned short* wres16 = (unsigned short*)(ws + off); off += (size_t)LSEQ * LSEQ / 2;
    unsigned short* t16  = yg16;   // mix1 out / mamba2 in (lifetimes disjoint)
    unsigned short* rT16 = sT16;   // residual transpose after mix1 consumed sT16
    (void)ws_size; (void)n_in; (void)in_sizes; (void)out_size;

    const dim3 blk(256);

    // ---- all input casts in one dispatch ----
    cast8<<<dim3(11392), blk, 0, stream>>>(
        x, bx, m1_Win, win1, m1_Wout, wout1, m2_Win, win2, m2_Wout, wout2,
        W_spa, wspa16, W_mid, wmid16, W_res, wres16);
    // ---- both Wcomb = Wdt @ Wx[:64] ----
    gemm_nn_wcomb<<<dim3(16, 16, 2), blk, 0, stream>>>(
        m1_Wdt, m1_Wx, wcomb1, m2_Wdt, m2_Wx, wcomb2);

    auto mamba = [&](const unsigned short* inp16, const unsigned short* win16,
                     const unsigned short* wcomb16, const unsigned short* wout16,
                     const float* convw, const float* convb, const float* Wx,
                     const float* bdt, const float* Alog, const float* Dp,
                     float* out_buf) {
        // xz16 = bf16(inp @ Win.T) : (4096,2048)  [2048 blocks, SWZ=2]
        gemm_sk<0, 1, 0, 0, 2><<<dim3(TWO_DI / 64, NROWS / 64), blk, 0, stream>>>(
            (const short*)inp16, (const short*)win16, nullptr, nullptr,
            (void*)xz16, NROWS, TWO_DI, DM);
        // conv + silu + fused B/C projection -> xi16, bc
        conv_silu_bc<<<dim3(NROWS), blk, 0, stream>>>(
            xz16, convw, convb, Wx, xi16, buf_bc);
        // dt16 = bf16(softplus(xi @ Wcomb.T + bdt))  [1024 blocks, SWZ=1]
        gemm_sk<1, 1, 0, 0, 1><<<dim3(DI / 64, NROWS / 64), blk, 0, stream>>>(
            (const short*)xi16, (const short*)wcomb16, bdt, nullptr,
            (void*)dt16, NROWS, DI, DI);
        // chunked scan -> yg16
        scan_part1<<<dim3(DI / 256, BATCH, NCH), blk, 0, stream>>>(
            dt16, xi16, buf_bc, Alog, buf_hc);
        scan_carry<<<dim3(DI / 256, BATCH), blk, 0, stream>>>(buf_hc, buf_ci);
        scan_part2<<<dim3(DI / 256, BATCH, NCH), blk, 0, stream>>>(
            dt16, xi16, xz16, buf_bc, Alog, Dp, buf_ci, yg16);
        // out = yg @ Wout.T : (4096,1024) fp32  [1024 blocks, SWZ=1]
        gemm_sk<0, 0, 0, 0, 1><<<dim3(DM / 64, NROWS / 64), blk, 0, stream>>>(
            (const short*)yg16, (const short*)wout16, nullptr, nullptr,
            (void*)out_buf, NROWS, DM, DI);
    };

    // ---- Mamba 1 + LN1 ----
    mamba(bx, win1, wcomb1, wout1, m1_convw, m1_convb, m1_Wx, m1_bdt,
          m1_Alog, m1_D, buf_s);
    ln_kernel<<<dim3(NROWS), blk, 0, stream>>>(buf_s, ln1_g, ln1_b);

    // ---- channel mix 1: t16[b] = bf16(silu(W_mid @ s[b])) ----
    transpose_cast<<<dim3(32, 8, BATCH), blk, 0, stream>>>(buf_s, sT16);
    gemm_sk<3, 1, 1, 0, 0><<<dim3(DM / 64, LSEQ / 64, BATCH), blk, 0, stream>>>(
        (const short*)wmid16, (const short*)sT16, nullptr, nullptr,
        (void*)t16, LSEQ, DM, LSEQ);

    // ---- Mamba 2 + LN2 ----
    mamba(t16, win2, wcomb2, wout2, m2_convw, m2_convb, m2_Wx, m2_bdt,
          m2_Alog, m2_D, buf_s);
    ln_kernel<<<dim3(NROWS), blk, 0, stream>>>(buf_s, ln2_g, ln2_b);

    // ---- residual path: res16 = bf16(silu(x @ W_spa.T + b_spa))  [SWZ=1] ----
    gemm_sk<2, 1, 0, 0, 1><<<dim3(DM / 64, NROWS / 64), blk, 0, stream>>>(
        (const short*)bx, (const short*)wspa16, b_spa, nullptr,
        (void*)res16, NROWS, DM, DM);
    transpose16<<<dim3(32, 8, BATCH), blk, 0, stream>>>(res16, rT16);
    // mix2 + final fuse: d_out = silu(s + silu(W_res @ r))
    gemm_sk<3, 0, 1, 1, 0><<<dim3(DM / 64, LSEQ / 64, BATCH), blk, 0, stream>>>(
        (const short*)wres16, (const short*)rT16, nullptr, buf_s,
        d_out, LSEQ, DM, LSEQ);
}